// Round 1
// baseline (644.412 us; speedup 1.0000x reference)
//
#include <hip/hip_runtime.h>
#include <hip/hip_bf16.h>
#include <cstdint>

using bf16 = __hip_bfloat16;
typedef __attribute__((ext_vector_type(8))) short bf16x8v;
typedef __attribute__((ext_vector_type(4))) float f32x4v;

#define BM 128
#define BN 128
#define BK 64
#define LDS_TILE_BYTES 16384  // 128 rows * 64 cols * 2B

// ---------------------------------------------------------------------------
// async global->LDS, 16B per lane. LDS dest is wave-uniform segment base.
// Swizzled LDS layout realized by pre-swizzling the per-lane GLOBAL source
// (global_load_lds writes linearly: base + lane*16).
// ---------------------------------------------------------------------------
__device__ __forceinline__ void gload_lds16(const void* g, void* l) {
  __builtin_amdgcn_global_load_lds(
      (const __attribute__((address_space(1))) void*)g,
      (__attribute__((address_space(3))) void*)l, 16, 0, 0);
}

// ---------------------------------------------------------------------------
// Generic batched "bt" GEMM: C[m,n] = scale * sum_k A[m,k]*B[n,k]
// A,B bf16 row-major (K fastest). 4-level batch decode via strides.
// M,N multiples of 128; K multiple of 64 (all shapes here satisfy this).
// ---------------------------------------------------------------------------
struct GemmP {
  const bf16* A; const bf16* B; void* C;
  int K, lda, ldb, ldc, tilesN;
  int d0, d1, d2;
  long long sA0, sA1, sA2, sA3;
  long long sB0, sB1, sB2, sB3;
  long long sC0, sC1, sC2, sC3;
  float scale;
};

template<int OUT_F32>
__global__ __launch_bounds__(256, 2)
void gemm_bt(GemmP p)
{
  __shared__ __attribute__((aligned(1024))) char smem[2 * LDS_TILE_BYTES];
  const int tid  = threadIdx.x;
  const int lane = tid & 63;
  const int wid  = tid >> 6;

  const int tn = blockIdx.x % p.tilesN;
  const int tm = blockIdx.x / p.tilesN;
  int idx = blockIdx.y;
  const int i0 = idx % p.d0; idx /= p.d0;
  const int i1 = idx % p.d1; idx /= p.d1;
  const int i2 = idx % p.d2;
  const int i3 = idx / p.d2;

  const bf16* Am = p.A + ((long long)i0*p.sA0 + (long long)i1*p.sA1 +
                          (long long)i2*p.sA2 + (long long)i3*p.sA3);
  const bf16* Bm = p.B + ((long long)i0*p.sB0 + (long long)i1*p.sB1 +
                          (long long)i2*p.sB2 + (long long)i3*p.sB3);
  const int bm = tm * BM, bn = tn * BN;

  // Staging map: 16 segments of 1024B per tile; wave w owns segments w*4..w*4+3.
  // LDS slot o (linear) holds chunk c = ((o>>4)&7) ^ (row&7) of row o>>7
  // => swizzled layout byte(row,c) = row*128 + ((c ^ (row&7))<<4).
  const bf16* asrc[4]; const bf16* bsrc[4]; int lseg[4];
  #pragma unroll
  for (int r = 0; r < 4; ++r) {
    const int oseg = (wid*4 + r) * 1024;
    const int o    = oseg + lane*16;
    const int row  = o >> 7;
    const int ch   = ((o >> 4) & 7) ^ (row & 7);
    lseg[r] = oseg;
    asrc[r] = Am + (size_t)(bm + row) * p.lda + ch*8;
    bsrc[r] = Bm + (size_t)(bn + row) * p.ldb + ch*8;
  }

  f32x4v acc[4][4];
  #pragma unroll
  for (int i = 0; i < 4; ++i)
    #pragma unroll
    for (int j = 0; j < 4; ++j) acc[i][j] = (f32x4v){0.f, 0.f, 0.f, 0.f};

  const int wr = wid >> 1, wc = wid & 1;
  const int fr_a = wr*64 + (lane & 15);
  const int fr_b = wc*64 + (lane & 15);
  const int fch  = lane >> 4;

  const int nK = p.K / BK;
  for (int kt = 0; kt < nK; ++kt) {
    #pragma unroll
    for (int r = 0; r < 4; ++r) {
      gload_lds16(asrc[r], smem + lseg[r]);
      gload_lds16(bsrc[r], smem + LDS_TILE_BYTES + lseg[r]);
      asrc[r] += BK; bsrc[r] += BK;
    }
    __syncthreads();
    #pragma unroll
    for (int kk = 0; kk < 2; ++kk) {
      bf16x8v a[4], b[4];
      #pragma unroll
      for (int mi = 0; mi < 4; ++mi) {
        const int row = fr_a + mi*16;
        const int by  = row*128 + (((fch + kk*4) ^ (row & 7)) << 4);
        a[mi] = *(const bf16x8v*)(smem + by);
      }
      #pragma unroll
      for (int ni = 0; ni < 4; ++ni) {
        const int row = fr_b + ni*16;
        const int by  = LDS_TILE_BYTES + row*128 + (((fch + kk*4) ^ (row & 7)) << 4);
        b[ni] = *(const bf16x8v*)(smem + by);
      }
      #pragma unroll
      for (int mi = 0; mi < 4; ++mi)
        #pragma unroll
        for (int ni = 0; ni < 4; ++ni)
          acc[mi][ni] = __builtin_amdgcn_mfma_f32_16x16x32_bf16(a[mi], b[ni], acc[mi][ni], 0, 0, 0);
    }
    __syncthreads();
  }

  // Epilogue. C/D 16x16 mapping: col = lane&15, row = (lane>>4)*4 + reg.
  const long long coff = (long long)i0*p.sC0 + (long long)i1*p.sC1 +
                         (long long)i2*p.sC2 + (long long)i3*p.sC3;
  const int col0 = bn + wc*64 + (lane & 15);
  const int row0 = bm + wr*64 + ((lane >> 4) << 2);
  if (OUT_F32) {
    float* Cp = (float*)p.C + coff;
    #pragma unroll
    for (int mi = 0; mi < 4; ++mi)
      #pragma unroll
      for (int ni = 0; ni < 4; ++ni)
        #pragma unroll
        for (int j = 0; j < 4; ++j)
          Cp[(size_t)(row0 + mi*16 + j) * p.ldc + (col0 + ni*16)] = acc[mi][ni][j] * p.scale;
  } else {
    bf16* Cp = (bf16*)p.C + coff;
    #pragma unroll
    for (int mi = 0; mi < 4; ++mi)
      #pragma unroll
      for (int ni = 0; ni < 4; ++ni)
        #pragma unroll
        for (int j = 0; j < 4; ++j)
          Cp[(size_t)(row0 + mi*16 + j) * p.ldc + (col0 + ni*16)] =
              __float2bfloat16(acc[mi][ni][j] * p.scale);
  }
}

// ---------------------------------------------------------------------------
// fp32 -> bf16 conversion (vectorized 4/thread)
// ---------------------------------------------------------------------------
__device__ __forceinline__ unsigned short f2bu(float x) {
  union { __hip_bfloat16 h; unsigned short u; } cv;
  cv.h = __float2bfloat16(x);
  return cv.u;
}

__global__ void cvt_f32_bf16(const float* __restrict__ in, unsigned short* __restrict__ out, int n4) {
  int i = blockIdx.x * 256 + threadIdx.x;
  if (i >= n4) return;
  const float4 v = ((const float4*)in)[i];
  ushort4 o;
  o.x = f2bu(v.x); o.y = f2bu(v.y); o.z = f2bu(v.z); o.w = f2bu(v.w);
  ((ushort4*)out)[i] = o;
}

// Wpre[w][o][h*256 + i] = W_w[o][i*4 + h]   (head-interleave -> head-blocked)
__global__ void wpre_kernel(const float* __restrict__ Wout, const float* __restrict__ Woutd,
                            bf16* __restrict__ Wpre) {
  const int w = blockIdx.y;
  const int flat = blockIdx.x * 256 + threadIdx.x;   // 0..1M-1
  const float* Wsrc = w ? Woutd : Wout;
  const int o  = flat >> 10;
  const int c2 = flat & 1023;
  const int h  = c2 >> 8;
  const int i  = c2 & 255;
  Wpre[(size_t)w * 1048576 + flat] = __float2bfloat16(Wsrc[o * 1024 + i * 4 + h]);
}

// ---------------------------------------------------------------------------
// InstanceNorm over the whole [256,256] score matrix per (pp,b,h), then
// row-softmax over j. scores are already scaled by 1/sqrt(1024); eps=1e-5
// applies to the variance of the SCALED scores (it matters: var ~ 1e-5).
// ---------------------------------------------------------------------------
__global__ __launch_bounds__(256)
void inorm_softmax(const float* __restrict__ sc, bf16* __restrict__ pr) {
  const int bidx = blockIdx.x;
  const float* s = sc + (size_t)bidx * 65536;
  bf16* p = pr + (size_t)bidx * 65536;
  const int tid = threadIdx.x, lane = tid & 63, w = tid >> 6;

  float sum = 0.f, sq = 0.f;
  for (int i = tid; i < 16384; i += 256) {
    const float4 v = ((const float4*)s)[i];
    sum += (v.x + v.y) + (v.z + v.w);
    sq  += (v.x*v.x + v.y*v.y) + (v.z*v.z + v.w*v.w);
  }
  #pragma unroll
  for (int o = 32; o; o >>= 1) { sum += __shfl_xor(sum, o); sq += __shfl_xor(sq, o); }
  __shared__ float red[8];
  if (lane == 0) { red[w] = sum; red[4 + w] = sq; }
  __syncthreads();
  sum = red[0] + red[1] + red[2] + red[3];
  sq  = red[4] + red[5] + red[6] + red[7];
  const float mean = sum * (1.f / 65536.f);
  const float var  = sq * (1.f / 65536.f) - mean * mean;
  const float inv  = rsqrtf(var + 1e-5f);

  for (int row = w; row < 256; row += 4) {
    const float* sr = s + row * 256;
    float x0 = (sr[lane]       - mean) * inv;
    float x1 = (sr[lane + 64]  - mean) * inv;
    float x2 = (sr[lane + 128] - mean) * inv;
    float x3 = (sr[lane + 192] - mean) * inv;
    float mx = fmaxf(fmaxf(x0, x1), fmaxf(x2, x3));
    #pragma unroll
    for (int o = 32; o; o >>= 1) mx = fmaxf(mx, __shfl_xor(mx, o));
    float e0 = expf(x0 - mx), e1 = expf(x1 - mx), e2 = expf(x2 - mx), e3 = expf(x3 - mx);
    float se = (e0 + e1) + (e2 + e3);
    #pragma unroll
    for (int o = 32; o; o >>= 1) se += __shfl_xor(se, o);
    const float rvs = 1.f / se;
    bf16* pro = p + row * 256;
    pro[lane]       = __float2bfloat16(e0 * rvs);
    pro[lane + 64]  = __float2bfloat16(e1 * rvs);
    pro[lane + 128] = __float2bfloat16(e2 * rvs);
    pro[lane + 192] = __float2bfloat16(e3 * rvs);
  }
}

// ---------------------------------------------------------------------------
// Host orchestration
// ---------------------------------------------------------------------------
extern "C" void kernel_launch(void* const* d_in, const int* in_sizes, int n_in,
                              void* d_out, int out_size, void* d_ws, size_t ws_size,
                              hipStream_t stream)
{
  const float* S     = (const float*)d_in[0];
  const float* SKV   = (const float*)d_in[1];
  const float* T     = (const float*)d_in[2];
  const float* TKV   = (const float*)d_in[3];
  const float* Wq    = (const float*)d_in[4];
  const float* Wk    = (const float*)d_in[5];
  const float* Wv    = (const float*)d_in[6];
  const float* Wout  = (const float*)d_in[7];
  const float* Woutd = (const float*)d_in[8];
  float* out = (float*)d_out;

  const int Bd = 4, Nd = 4096, Cd = 1024, Hd = 4, Dd = 256;
  const long long NC  = (long long)Nd * Cd;   // 4,194,304
  const long long BNC = (long long)Bd * NC;   // 16,777,216

  char* ws = (char*)d_ws;
  size_t off = 0;
  auto alloc = [&](size_t bytes) -> void* {
    void* pp = ws + off; off += (bytes + 255) & ~(size_t)255; return pp;
  };
  // Xbf order: [S, T, SKV, TKV] so qi/ki batch strides are linear (BNC).
  bf16*  Xbf    = (bf16*)alloc(4 * BNC * 2);
  bf16*  Wqb    = (bf16*)alloc((size_t)Hd * Dd * Dd * 2);
  bf16*  Wkb    = (bf16*)alloc((size_t)Hd * Dd * Dd * 2);
  bf16*  Wvb    = (bf16*)alloc((size_t)Hd * Dd * Dd * 2);
  bf16*  Wpre   = (bf16*)alloc(2 * (size_t)Cd * Cd * 2);
  bf16*  QT     = (bf16*)alloc(2 * BNC * 2);   // [qi][b][h][i][n]
  bf16*  KT     = (bf16*)alloc(2 * BNC * 2);   // [ki][b][h][j][n]
  bf16*  VT     = (bf16*)alloc(2 * BNC * 2);   // [vi][b][h][n][j]
  float* scores = (float*)alloc(64ull * 65536 * 4);  // [pp][b][h][i][j]
  bf16*  probs  = (bf16*)alloc(64ull * 65536 * 2);
  bf16*  ctx    = Xbf;  // reuse: Xbf dead after projections
  if (ws_size < off) return;  // insufficient scratch -> fail validation cleanly

  // 1) conversions
  auto cvt = [&](const float* in, bf16* o, long long n) {
    int n4 = (int)(n / 4);
    cvt_f32_bf16<<<dim3((n4 + 255) / 256), dim3(256), 0, stream>>>(in, (unsigned short*)o, n4);
  };
  cvt(S,   Xbf + 0 * BNC, BNC);
  cvt(T,   Xbf + 1 * BNC, BNC);
  cvt(SKV, Xbf + 2 * BNC, BNC);
  cvt(TKV, Xbf + 3 * BNC, BNC);
  cvt(Wq, Wqb, (long long)Hd * Dd * Dd);
  cvt(Wk, Wkb, (long long)Hd * Dd * Dd);
  cvt(Wv, Wvb, (long long)Hd * Dd * Dd);
  wpre_kernel<<<dim3(4096, 2), dim3(256), 0, stream>>>(Wout, Woutd, Wpre);

  const long long HDN = (long long)Dd * Nd;  // 1,048,576 (per-h in QT/KT/VT)
  GemmP g{};

  // 2) Q projection: Qt[qi][b][h][i][n] = sum_d Wq[h][i][d] * X_qi[b][n][h*D+d]
  g.A = Wqb; g.B = Xbf; g.C = QT;
  g.K = 256; g.lda = 256; g.ldb = 1024; g.ldc = 4096; g.tilesN = 32;
  g.d0 = 4; g.d1 = 4; g.d2 = 2;                       // (h, b, qi)
  g.sA0 = 65536; g.sA1 = 0;  g.sA2 = 0;   g.sA3 = 0;
  g.sB0 = 256;   g.sB1 = NC; g.sB2 = BNC; g.sB3 = 0;
  g.sC0 = HDN;   g.sC1 = NC; g.sC2 = BNC; g.sC3 = 0;
  g.scale = 1.f;
  gemm_bt<0><<<dim3(2 * 32, 32), dim3(256), 0, stream>>>(g);

  // 3) K projection (input SKV/TKV)
  g.A = Wkb; g.B = Xbf + 2 * BNC; g.C = KT;
  gemm_bt<0><<<dim3(2 * 32, 32), dim3(256), 0, stream>>>(g);

  // 4) V projection: V[vi][b][h][n][j] = sum_d X_vi[b][n][h*D+d] * Wv[h][j][d]
  g.A = Xbf + 2 * BNC; g.B = Wvb; g.C = VT;
  g.K = 256; g.lda = 1024; g.ldb = 256; g.ldc = 256; g.tilesN = 2;
  g.sA0 = 256;   g.sA1 = NC; g.sA2 = BNC; g.sA3 = 0;
  g.sB0 = 65536; g.sB1 = 0;  g.sB2 = 0;   g.sB3 = 0;
  g.sC0 = HDN;   g.sC1 = NC; g.sC2 = BNC; g.sC3 = 0;
  gemm_bt<0><<<dim3(32 * 2, 32), dim3(256), 0, stream>>>(g);

  // 5) scores[pp][b][h][i][j] = (1/32) sum_n Qt[qi][i,n] * Kt[ki][j,n], pp = 2*qi+ki
  g.A = QT; g.B = KT; g.C = scores;
  g.K = 4096; g.lda = 4096; g.ldb = 4096; g.ldc = 256; g.tilesN = 2;
  g.d0 = 4; g.d1 = 4; g.d2 = 2;                       // (h, b, ki, qi)
  g.sA0 = HDN;   g.sA1 = NC;     g.sA2 = 0;       g.sA3 = BNC;
  g.sB0 = HDN;   g.sB1 = NC;     g.sB2 = BNC;     g.sB3 = 0;
  g.sC0 = 65536; g.sC1 = 262144; g.sC2 = 1048576; g.sC3 = 2097152;
  g.scale = 0.03125f;  // 1/sqrt(1024)
  gemm_bt<1><<<dim3(2 * 2, 64), dim3(256), 0, stream>>>(g);

  // 6) InstanceNorm + softmax -> probs (bf16)
  inorm_softmax<<<dim3(64), dim3(256), 0, stream>>>(scores, probs);

  // 7) ctx[pp][b][n][h*D+i] = sum_j V[ki][b,h][n,j] * probs[pp][b,h][i,j]
  g.A = VT; g.B = probs; g.C = ctx;
  g.K = 256; g.lda = 256; g.ldb = 256; g.ldc = 1024; g.tilesN = 2;
  g.sA0 = HDN;   g.sA1 = NC;     g.sA2 = BNC;     g.sA3 = 0;
  g.sB0 = 65536; g.sB1 = 262144; g.sB2 = 1048576; g.sB3 = 2097152;
  g.sC0 = 256;   g.sC1 = NC;     g.sC2 = BNC;     g.sC3 = 2 * BNC;
  g.scale = 1.f;
  gemm_bt<0><<<dim3(32 * 2, 64), dim3(256), 0, stream>>>(g);

  // 8) out[slot][b*N+n][o] = sum_c ctx[pp][b,n,c] * Wpre[qi][o,c]; slot = qi+2*ki
  g.A = ctx; g.B = Wpre; g.C = out;
  g.K = 1024; g.lda = 1024; g.ldb = 1024; g.ldc = 1024; g.tilesN = 8;
  g.d0 = 1; g.d1 = 1; g.d2 = 2;                       // (-, -, ki, qi)
  g.sA0 = 0; g.sA1 = 0; g.sA2 = BNC;     g.sA3 = 2 * BNC;
  g.sB0 = 0; g.sB1 = 0; g.sB2 = 0;       g.sB3 = 1048576;
  g.sC0 = 0; g.sC1 = 0; g.sC2 = 2 * BNC; g.sC3 = BNC;
  g.scale = 1.f;
  gemm_bt<1><<<dim3(128 * 8, 4), dim3(256), 0, stream>>>(g);

  (void)in_sizes; (void)n_in; (void)out_size;
}

// Round 2
// 545.948 us; speedup vs baseline: 1.1804x; 1.1804x over previous
//
#include <hip/hip_runtime.h>
#include <hip/hip_bf16.h>
#include <cstdint>

using bf16 = __hip_bfloat16;
typedef __attribute__((ext_vector_type(8))) short bf16x8v;
typedef __attribute__((ext_vector_type(4))) float f32x4v;

#define BM 128
#define BN 128
#define BK 64
#define LDS_TILE_BYTES 16384  // 128 rows * 64 cols * 2B

__device__ __forceinline__ void gload_lds16(const void* g, void* l) {
  __builtin_amdgcn_global_load_lds(
      (const __attribute__((address_space(1))) void*)g,
      (__attribute__((address_space(3))) void*)l, 16, 0, 0);
}

// ---------------------------------------------------------------------------
// Generic batched "bt" GEMM: C[m,n] = scale * sum_k A[m,k]*B[n,k]
// A,B bf16 row-major (K fastest). 4-level batch decode via strides.
// ---------------------------------------------------------------------------
struct GemmP {
  const bf16* A; const bf16* B; void* C;
  int K, lda, ldb, ldc, tilesN, swz;
  int d0, d1, d2;
  long long sA0, sA1, sA2, sA3;
  long long sB0, sB1, sB2, sB3;
  long long sC0, sC1, sC2, sC3;
  float scale;
};

template<int OUT_F32>
__global__ __launch_bounds__(256, 4)
void gemm_bt(GemmP p)
{
  __shared__ __attribute__((aligned(1024))) char smem[2 * LDS_TILE_BYTES];
  const int tid  = threadIdx.x;
  const int lane = tid & 63;
  const int wid  = tid >> 6;

  // XCD-aware bijective swizzle (T1): co-locate tn-consecutive tiles per XCD.
  int bx = blockIdx.x;
  if (p.swz) {
    const int nx = gridDim.x;
    const int q = nx >> 3, r = nx & 7;
    const int xcd = bx & 7, loc = bx >> 3;
    bx = (xcd < r ? xcd * (q + 1) : r * (q + 1) + (xcd - r) * q) + loc;
  }
  const int tn = bx % p.tilesN;
  const int tm = bx / p.tilesN;
  int idx = blockIdx.y;
  const int i0 = idx % p.d0; idx /= p.d0;
  const int i1 = idx % p.d1; idx /= p.d1;
  const int i2 = idx % p.d2;
  const int i3 = idx / p.d2;

  const bf16* Am = p.A + ((long long)i0*p.sA0 + (long long)i1*p.sA1 +
                          (long long)i2*p.sA2 + (long long)i3*p.sA3);
  const bf16* Bm = p.B + ((long long)i0*p.sB0 + (long long)i1*p.sB1 +
                          (long long)i2*p.sB2 + (long long)i3*p.sB3);
  const int bm = tm * BM, bn = tn * BN;

  // Staging map: 16 segments of 1024B per tile; wave w owns segments w*4..w*4+3.
  // LDS slot o (linear) holds chunk c = ((o>>4)&7) ^ (row&7) of row o>>7
  // => swizzled layout byte(row,c) = row*128 + ((c ^ (row&7))<<4).
  const bf16* asrc[4]; const bf16* bsrc[4]; int lseg[4];
  #pragma unroll
  for (int r = 0; r < 4; ++r) {
    const int oseg = (wid*4 + r) * 1024;
    const int o    = oseg + lane*16;
    const int row  = o >> 7;
    const int ch   = ((o >> 4) & 7) ^ (row & 7);
    lseg[r] = oseg;
    asrc[r] = Am + (size_t)(bm + row) * p.lda + ch*8;
    bsrc[r] = Bm + (size_t)(bn + row) * p.ldb + ch*8;
  }

  f32x4v acc[4][4];
  #pragma unroll
  for (int i = 0; i < 4; ++i)
    #pragma unroll
    for (int j = 0; j < 4; ++j) acc[i][j] = (f32x4v){0.f, 0.f, 0.f, 0.f};

  const int wr = wid >> 1, wc = wid & 1;
  const int fr_a = wr*64 + (lane & 15);
  const int fr_b = wc*64 + (lane & 15);
  const int fch  = lane >> 4;

  const int nK = p.K / BK;
  for (int kt = 0; kt < nK; ++kt) {
    #pragma unroll
    for (int r = 0; r < 4; ++r) {
      gload_lds16(asrc[r], smem + lseg[r]);
      gload_lds16(bsrc[r], smem + LDS_TILE_BYTES + lseg[r]);
      asrc[r] += BK; bsrc[r] += BK;
    }
    __syncthreads();
    #pragma unroll
    for (int kk = 0; kk < 2; ++kk) {
      bf16x8v a[4], b[4];
      #pragma unroll
      for (int mi = 0; mi < 4; ++mi) {
        const int row = fr_a + mi*16;
        const int by  = row*128 + (((fch + kk*4) ^ (row & 7)) << 4);
        a[mi] = *(const bf16x8v*)(smem + by);
      }
      #pragma unroll
      for (int ni = 0; ni < 4; ++ni) {
        const int row = fr_b + ni*16;
        const int by  = LDS_TILE_BYTES + row*128 + (((fch + kk*4) ^ (row & 7)) << 4);
        b[ni] = *(const bf16x8v*)(smem + by);
      }
      #pragma unroll
      for (int mi = 0; mi < 4; ++mi)
        #pragma unroll
        for (int ni = 0; ni < 4; ++ni)
          acc[mi][ni] = __builtin_amdgcn_mfma_f32_16x16x32_bf16(a[mi], b[ni], acc[mi][ni], 0, 0, 0);
    }
    __syncthreads();
  }

  // Epilogue. C/D 16x16 mapping: col = lane&15, row = (lane>>4)*4 + reg.
  const long long coff = (long long)i0*p.sC0 + (long long)i1*p.sC1 +
                         (long long)i2*p.sC2 + (long long)i3*p.sC3;
  const int col0 = bn + wc*64 + (lane & 15);
  const int row0 = bm + wr*64 + ((lane >> 4) << 2);
  if (OUT_F32) {
    float* Cp = (float*)p.C + coff;
    #pragma unroll
    for (int mi = 0; mi < 4; ++mi)
      #pragma unroll
      for (int ni = 0; ni < 4; ++ni)
        #pragma unroll
        for (int j = 0; j < 4; ++j)
          Cp[(size_t)(row0 + mi*16 + j) * p.ldc + (col0 + ni*16)] = acc[mi][ni][j] * p.scale;
  } else {
    bf16* Cp = (bf16*)p.C + coff;
    #pragma unroll
    for (int mi = 0; mi < 4; ++mi)
      #pragma unroll
      for (int ni = 0; ni < 4; ++ni)
        #pragma unroll
        for (int j = 0; j < 4; ++j)
          Cp[(size_t)(row0 + mi*16 + j) * p.ldc + (col0 + ni*16)] =
              __float2bfloat16(acc[mi][ni][j] * p.scale);
  }
}

// ---------------------------------------------------------------------------
// fp32 -> bf16 conversions
// ---------------------------------------------------------------------------
__device__ __forceinline__ unsigned short f2bu(float x) {
  union { __hip_bfloat16 h; unsigned short u; } cv;
  cv.h = __float2bfloat16(x);
  return cv.u;
}

// 4 equal-size sources selected by blockIdx.y; outputs contiguous at stride.
__global__ void cvt4_f32_bf16(const float* __restrict__ a0, const float* __restrict__ a1,
                              const float* __restrict__ a2, const float* __restrict__ a3,
                              unsigned short* __restrict__ out, long long ostride, int n4) {
  const int i = blockIdx.x * 256 + threadIdx.x;
  if (i >= n4) return;
  const float* src = (blockIdx.y == 0) ? a0 : (blockIdx.y == 1) ? a1 : (blockIdx.y == 2) ? a2 : a3;
  const float4 v = ((const float4*)src)[i];
  ushort4 o;
  o.x = f2bu(v.x); o.y = f2bu(v.y); o.z = f2bu(v.z); o.w = f2bu(v.w);
  ((ushort4*)(out + (size_t)blockIdx.y * ostride))[i] = o;
}

__global__ void cvt3_f32_bf16(const float* __restrict__ a0, const float* __restrict__ a1,
                              const float* __restrict__ a2,
                              unsigned short* __restrict__ out, long long ostride, int n4) {
  const int i = blockIdx.x * 256 + threadIdx.x;
  if (i >= n4) return;
  const float* src = (blockIdx.y == 0) ? a0 : (blockIdx.y == 1) ? a1 : a2;
  const float4 v = ((const float4*)src)[i];
  ushort4 o;
  o.x = f2bu(v.x); o.y = f2bu(v.y); o.z = f2bu(v.z); o.w = f2bu(v.w);
  ((ushort4*)(out + (size_t)blockIdx.y * ostride))[i] = o;
}

// Wpre[w][o][h*256 + i] = W_w[o][i*4 + h]   (head-interleave -> head-blocked)
__global__ void wpre_kernel(const float* __restrict__ Wout, const float* __restrict__ Woutd,
                            bf16* __restrict__ Wpre) {
  const int w = blockIdx.y;
  const int flat = blockIdx.x * 256 + threadIdx.x;   // 0..1M-1
  const float* Wsrc = w ? Woutd : Wout;
  const int o  = flat >> 10;
  const int c2 = flat & 1023;
  const int h  = c2 >> 8;
  const int i  = c2 & 255;
  Wpre[(size_t)w * 1048576 + flat] = __float2bfloat16(Wsrc[o * 1024 + i * 4 + h]);
}

// ---------------------------------------------------------------------------
// InstanceNorm + softmax on TRANSPOSED scores.
// Input scT[j][i] = scores[i][j] per (pp,b,h). Softmax over j (rows of scT)
// for each fixed column i => fully thread-local per column. Output probsT
// in the same [j][i] layout (= bt-form B operand of the Weff GEMM).
// ---------------------------------------------------------------------------
__global__ __launch_bounds__(256)
void inorm_softmax_t(const float* __restrict__ sc, bf16* __restrict__ pr) {
  const int bidx = blockIdx.x;
  const float* s = sc + (size_t)bidx * 65536;
  bf16* p = pr + (size_t)bidx * 65536;
  const int tid = threadIdx.x, lane = tid & 63, w = tid >> 6;

  float sum = 0.f, sq = 0.f;
  for (int i = tid; i < 16384; i += 256) {
    const float4 v = ((const float4*)s)[i];
    sum += (v.x + v.y) + (v.z + v.w);
    sq  += (v.x*v.x + v.y*v.y) + (v.z*v.z + v.w*v.w);
  }
  #pragma unroll
  for (int o = 32; o; o >>= 1) { sum += __shfl_xor(sum, o); sq += __shfl_xor(sq, o); }
  __shared__ float red[8];
  if (lane == 0) { red[w] = sum; red[4 + w] = sq; }
  __syncthreads();
  sum = red[0] + red[1] + red[2] + red[3];
  sq  = red[4] + red[5] + red[6] + red[7];
  const float mean = sum * (1.f / 65536.f);
  const float var  = sq * (1.f / 65536.f) - mean * mean;
  const float inv  = rsqrtf(var + 1e-5f);

  // column i = tid; rows j: coalesced across threads each iteration.
  const float* col = s + tid;
  float mx = -1e30f;
  #pragma unroll 8
  for (int j = 0; j < 256; ++j) mx = fmaxf(mx, col[(size_t)j * 256]);
  mx = (mx - mean) * inv;
  float se = 0.f;
  #pragma unroll 8
  for (int j = 0; j < 256; ++j) se += expf((col[(size_t)j * 256] - mean) * inv - mx);
  const float rvs = 1.f / se;
  bf16* pcol = p + tid;
  #pragma unroll 8
  for (int j = 0; j < 256; ++j)
    pcol[(size_t)j * 256] = __float2bfloat16(expf((col[(size_t)j * 256] - mean) * inv - mx) * rvs);
}

// ---------------------------------------------------------------------------
// Host orchestration
// ---------------------------------------------------------------------------
extern "C" void kernel_launch(void* const* d_in, const int* in_sizes, int n_in,
                              void* d_out, int out_size, void* d_ws, size_t ws_size,
                              hipStream_t stream)
{
  const float* S     = (const float*)d_in[0];
  const float* SKV   = (const float*)d_in[1];
  const float* T     = (const float*)d_in[2];
  const float* TKV   = (const float*)d_in[3];
  const float* Wq    = (const float*)d_in[4];
  const float* Wk    = (const float*)d_in[5];
  const float* Wv    = (const float*)d_in[6];
  const float* Wout  = (const float*)d_in[7];
  const float* Woutd = (const float*)d_in[8];
  float* out = (float*)d_out;

  const int Bd = 4, Nd = 4096, Cd = 1024, Hd = 4, Dd = 256;
  const long long NC  = (long long)Nd * Cd;   // 4,194,304
  const long long BNC = (long long)Bd * NC;   // 16,777,216

  char* ws = (char*)d_ws;
  size_t off = 0;
  auto alloc = [&](size_t bytes) -> void* {
    void* pp = ws + off; off += (bytes + 255) & ~(size_t)255; return pp;
  };
  // Xbf order: [S, T, SKV, TKV] so qi/ki batch strides are linear (BNC).
  bf16*  Xbf    = (bf16*)alloc(4 * BNC * 2);
  bf16*  Wqb    = (bf16*)alloc((size_t)Hd * Dd * Dd * 2);
  bf16*  Wkb    = (bf16*)alloc((size_t)Hd * Dd * Dd * 2);
  bf16*  Wvb    = (bf16*)alloc((size_t)Hd * Dd * Dd * 2);
  bf16*  Wpre   = (bf16*)alloc(2 * (size_t)Cd * Cd * 2);
  bf16*  QT     = (bf16*)alloc(2 * BNC * 2);   // [qi][b][h][i][n]
  bf16*  KT     = (bf16*)alloc(2 * BNC * 2);   // [ki][b][h][j][n]
  bf16*  Vc     = (bf16*)alloc(2 * BNC * 2);   // [vi][b][n][h*256+j]
  float* scores = (float*)alloc(64ull * 65536 * 4);  // scT: [pp][b][h][j][i]
  bf16*  probsT = (bf16*)alloc(64ull * 65536 * 2);   // [pp][b][h][j][i]
  bf16*  Weff   = QT;  // reuse: QT dead after scores GEMM; 32MB <= 64MB
  if (ws_size < off) return;

  // 1) conversions (fused launches)
  {
    const int n4 = (int)(BNC / 4);
    cvt4_f32_bf16<<<dim3((n4 + 255) / 256, 4), dim3(256), 0, stream>>>(
        S, T, SKV, TKV, (unsigned short*)Xbf, BNC, n4);
    const int w4 = (int)((Hd * Dd * Dd) / 4);
    cvt3_f32_bf16<<<dim3((w4 + 255) / 256, 3), dim3(256), 0, stream>>>(
        Wq, Wk, Wv, (unsigned short*)Wqb, (long long)Hd * Dd * Dd, w4);
    wpre_kernel<<<dim3(4096, 2), dim3(256), 0, stream>>>(Wout, Woutd, Wpre);
  }

  const long long HDN = (long long)Dd * Nd;  // 1,048,576
  GemmP g{};

  // 2) Q projection: Qt[qi][b][h][i][n] = sum_d Wq[h][i][d] * X_qi[b][n][h*D+d]
  g.A = Wqb; g.B = Xbf; g.C = QT;
  g.K = 256; g.lda = 256; g.ldb = 1024; g.ldc = 4096; g.tilesN = 32; g.swz = 0;
  g.d0 = 4; g.d1 = 4; g.d2 = 2;                       // (h, b, qi)
  g.sA0 = 65536; g.sA1 = 0;  g.sA2 = 0;   g.sA3 = 0;
  g.sB0 = 256;   g.sB1 = NC; g.sB2 = BNC; g.sB3 = 0;
  g.sC0 = HDN;   g.sC1 = NC; g.sC2 = BNC; g.sC3 = 0;
  g.scale = 1.f;
  gemm_bt<0><<<dim3(2 * 32, 32), dim3(256), 0, stream>>>(g);

  // 3) K projection (input SKV/TKV) -> KT [ki][b][h][j][n]
  g.A = Wkb; g.B = Xbf + 2 * BNC; g.C = KT;
  gemm_bt<0><<<dim3(2 * 32, 32), dim3(256), 0, stream>>>(g);

  // 4) V projection: Vc[vi][b][n][h*256+j] = sum_d X_vi[b][n][h*D+d] * Wv[h][j][d]
  g.A = Xbf + 2 * BNC; g.B = Wvb; g.C = Vc;
  g.K = 256; g.lda = 1024; g.ldb = 256; g.ldc = 1024; g.tilesN = 2; g.swz = 0;
  g.sA0 = 256;   g.sA1 = NC; g.sA2 = BNC; g.sA3 = 0;
  g.sB0 = 65536; g.sB1 = 0;  g.sB2 = 0;   g.sB3 = 0;
  g.sC0 = 256;   g.sC1 = NC; g.sC2 = BNC; g.sC3 = 0;
  gemm_bt<0><<<dim3(32 * 2, 32), dim3(256), 0, stream>>>(g);

  // 5) scT[pp][b][h][j][i] = (1/32) sum_n Kt[ki][j,n] * Qt[qi][i,n]  (pp=2qi+ki)
  g.A = KT; g.B = QT; g.C = scores;
  g.K = 4096; g.lda = 4096; g.ldb = 4096; g.ldc = 256; g.tilesN = 2; g.swz = 0;
  g.d0 = 4; g.d1 = 4; g.d2 = 2;                       // (h, b, ki, qi)
  g.sA0 = HDN;   g.sA1 = NC;     g.sA2 = BNC;     g.sA3 = 0;
  g.sB0 = HDN;   g.sB1 = NC;     g.sB2 = 0;       g.sB3 = BNC;
  g.sC0 = 65536; g.sC1 = 262144; g.sC2 = 1048576; g.sC3 = 2097152;
  g.scale = 0.03125f;  // 1/sqrt(1024)
  gemm_bt<1><<<dim3(2 * 2, 64), dim3(256), 0, stream>>>(g);

  // 6) InstanceNorm + softmax (column-local) -> probsT [pp][b][h][j][i]
  inorm_softmax_t<<<dim3(64), dim3(256), 0, stream>>>(scores, probsT);

  // 7) Weff[2qi+ki][b][o][h*256+j] = sum_i Wpre[qi][o][h*256+i] * probsT[pp][b][h][j][i]
  g.A = Wpre; g.B = probsT; g.C = Weff;
  g.K = 256; g.lda = 1024; g.ldb = 256; g.ldc = 1024; g.tilesN = 2; g.swz = 0;
  g.d0 = 4; g.d1 = 4; g.d2 = 2;                       // (h, b, ki, qi)
  g.sA0 = 256;   g.sA1 = 0;       g.sA2 = 0;       g.sA3 = 1048576;
  g.sB0 = 65536; g.sB1 = 262144;  g.sB2 = 1048576; g.sB3 = 2097152;
  g.sC0 = 256;   g.sC1 = 1048576; g.sC2 = 4194304; g.sC3 = 8388608;
  g.scale = 1.f;
  gemm_bt<0><<<dim3(8 * 2, 64), dim3(256), 0, stream>>>(g);

  // 8) out[slot][b][n][o] = sum_{h,j} Vc[ki][b][n][h*256+j] * Weff[2qi+ki][b][o][h*256+j]
  //    slot = qi + 2*ki
  g.A = Vc; g.B = Weff; g.C = out;
  g.K = 1024; g.lda = 1024; g.ldb = 1024; g.ldc = 1024; g.tilesN = 8; g.swz = 1;
  g.d0 = 4; g.d1 = 2; g.d2 = 2;                       // (b, ki, qi)
  g.sA0 = NC;      g.sA1 = BNC;     g.sA2 = 0;
  g.sB0 = 1048576; g.sB1 = 4194304; g.sB2 = 8388608;
  g.sC0 = NC;      g.sC1 = 2 * BNC; g.sC2 = BNC;
  g.sA3 = 0; g.sB3 = 0; g.sC3 = 0;
  g.scale = 1.f;
  gemm_bt<1><<<dim3(32 * 8, 16), dim3(256), 0, stream>>>(g);

  (void)in_sizes; (void)n_in; (void)out_size;
}

// Round 3
// 473.075 us; speedup vs baseline: 1.3622x; 1.1540x over previous
//
#include <hip/hip_runtime.h>
#include <hip/hip_bf16.h>
#include <cstdint>

using bf16 = __hip_bfloat16;
typedef __attribute__((ext_vector_type(8))) short bf16x8v;
typedef __attribute__((ext_vector_type(4))) float f32x4v;

__device__ __forceinline__ void gload_lds16(const void* g, void* l) {
  __builtin_amdgcn_global_load_lds(
      (const __attribute__((address_space(1))) void*)g,
      (__attribute__((address_space(3))) void*)l, 16, 0, 0);
}

__device__ __forceinline__ unsigned short f2bu(float x) {
  union { __hip_bfloat16 h; unsigned short u; } cv;
  cv.h = __float2bfloat16(x);
  return cv.u;
}

__device__ __forceinline__ bf16x8v cvt8(const f32x4v lo, const f32x4v hi) {
  bf16x8v t;
  t[0] = (short)f2bu(lo[0]); t[1] = (short)f2bu(lo[1]);
  t[2] = (short)f2bu(lo[2]); t[3] = (short)f2bu(lo[3]);
  t[4] = (short)f2bu(hi[0]); t[5] = (short)f2bu(hi[1]);
  t[6] = (short)f2bu(hi[2]); t[7] = (short)f2bu(hi[3]);
  return t;
}

// ---------------------------------------------------------------------------
// Generic batched "bt" GEMM: C[m,n] = scale * sum_k A[m,k]*B[n,k]
// A/B bf16 or fp32 (AF32/BF32 template: fp32 staged to LDS, converted to bf16
// at fragment read). 4-level batch decode + optional z-dim (split-K) strides.
// A2/B2: alternate base pointer selected when i2 != 0 (caller sets s?2 = 0).
// ---------------------------------------------------------------------------
struct GemmP {
  const void* A; const void* B; const void* A2; const void* B2; void* C;
  int K, lda, ldb, ldc, tilesN, swz;
  int d0, d1, d2;
  long long sA0, sA1, sA2, sA3;
  long long sB0, sB1, sB2, sB3;
  long long sC0, sC1, sC2, sC3;
  long long zA, zB, zC;
  float scale;
};

template<int OUT_F32, int AF32, int BF32>
__global__ __launch_bounds__(256, 4)
void gemm_bt(GemmP p)
{
  constexpr int EA = AF32 ? 4 : 2;
  constexpr int EB = BF32 ? 4 : 2;
  constexpr int ABYTES = 128 * 64 * EA;   // 16K or 32K
  constexpr int BBYTES = 128 * 64 * EB;
  constexpr int SEGA = ABYTES / 4096;     // segments per wave (4 or 8)
  constexpr int SEGB = BBYTES / 4096;
  __shared__ __attribute__((aligned(1024))) char smem[ABYTES + BBYTES];
  const int tid  = threadIdx.x;
  const int lane = tid & 63;
  const int wid  = tid >> 6;

  // XCD-aware bijective swizzle (T1)
  int bx = blockIdx.x;
  if (p.swz) {
    const int nx = gridDim.x;
    const int q = nx >> 3, r = nx & 7;
    const int xcd = bx & 7, loc = bx >> 3;
    bx = (xcd < r ? xcd * (q + 1) : r * (q + 1) + (xcd - r) * q) + loc;
  }
  const int tn = bx % p.tilesN;
  const int tm = bx / p.tilesN;
  int idx = blockIdx.y;
  const int i0 = idx % p.d0; idx /= p.d0;
  const int i1 = idx % p.d1; idx /= p.d1;
  const int i2 = idx % p.d2;
  const int i3 = idx / p.d2;

  const char* Abase = (const char*)((p.A2 && i2) ? p.A2 : p.A);
  const char* Bbase = (const char*)((p.B2 && i2) ? p.B2 : p.B);
  const long long offA = (long long)i0*p.sA0 + (long long)i1*p.sA1 +
                         (long long)i2*p.sA2 + (long long)i3*p.sA3 +
                         (long long)blockIdx.z*p.zA;
  const long long offB = (long long)i0*p.sB0 + (long long)i1*p.sB1 +
                         (long long)i2*p.sB2 + (long long)i3*p.sB3 +
                         (long long)blockIdx.z*p.zB;
  const char* Am = Abase + offA * EA;
  const char* Bm = Bbase + offB * EB;
  const int bm = tm * 128, bn = tn * 128;

  // Staging maps. bf16 tile: 128B rows, 8x16B slots, swz s^(row&7).
  // fp32 tile: 256B rows, 16x16B slots, swz s^(row&15). global_load_lds
  // writes linearly (base + lane*16) so the swizzle is realized by
  // pre-swizzling the per-lane GLOBAL source address (involution).
  const char* asrc[SEGA]; int aseg[SEGA];
  #pragma unroll
  for (int r = 0; r < SEGA; ++r) {
    const int oseg = (wid * SEGA + r) * 1024;
    const int o = oseg + lane * 16;
    int row, srcoff;
    if constexpr (AF32) { row = o >> 8; const int s = (o >> 4) & 15; srcoff = (s ^ (row & 15)) * 4; }
    else               { row = o >> 7; const int s = (o >> 4) & 7;  srcoff = (s ^ (row & 7)) * 8;  }
    aseg[r] = oseg;
    asrc[r] = Am + ((long long)(bm + row) * p.lda + srcoff) * EA;
  }
  const char* bsrc[SEGB]; int bseg[SEGB];
  #pragma unroll
  for (int r = 0; r < SEGB; ++r) {
    const int oseg = (wid * SEGB + r) * 1024;
    const int o = oseg + lane * 16;
    int row, srcoff;
    if constexpr (BF32) { row = o >> 8; const int s = (o >> 4) & 15; srcoff = (s ^ (row & 15)) * 4; }
    else               { row = o >> 7; const int s = (o >> 4) & 7;  srcoff = (s ^ (row & 7)) * 8;  }
    bseg[r] = oseg;
    bsrc[r] = Bm + ((long long)(bn + row) * p.ldb + srcoff) * EB;
  }

  f32x4v acc[4][4];
  #pragma unroll
  for (int i = 0; i < 4; ++i)
    #pragma unroll
    for (int j = 0; j < 4; ++j) acc[i][j] = (f32x4v){0.f, 0.f, 0.f, 0.f};

  const int wr = wid >> 1, wc = wid & 1;
  const int fr_a = wr * 64 + (lane & 15);
  const int fr_b = wc * 64 + (lane & 15);
  const int fch  = lane >> 4;

  const int nK = p.K / 64;
  for (int kt = 0; kt < nK; ++kt) {
    #pragma unroll
    for (int r = 0; r < SEGA; ++r) { gload_lds16(asrc[r], smem + aseg[r]); asrc[r] += 64 * EA; }
    #pragma unroll
    for (int r = 0; r < SEGB; ++r) { gload_lds16(bsrc[r], smem + ABYTES + bseg[r]); bsrc[r] += 64 * EB; }
    __syncthreads();
    #pragma unroll
    for (int kk = 0; kk < 2; ++kk) {
      bf16x8v a[4], b[4];
      #pragma unroll
      for (int mi = 0; mi < 4; ++mi) {
        const int row = fr_a + mi * 16;
        if constexpr (AF32) {
          const int c2 = (fch + kk * 4) * 2;
          const f32x4v lo = *(const f32x4v*)(smem + row * 256 + ((c2 ^ (row & 15)) << 4));
          const f32x4v hi = *(const f32x4v*)(smem + row * 256 + (((c2 + 1) ^ (row & 15)) << 4));
          a[mi] = cvt8(lo, hi);
        } else {
          a[mi] = *(const bf16x8v*)(smem + row * 128 + (((fch + kk * 4) ^ (row & 7)) << 4));
        }
      }
      #pragma unroll
      for (int ni = 0; ni < 4; ++ni) {
        const int row = fr_b + ni * 16;
        if constexpr (BF32) {
          const int c2 = (fch + kk * 4) * 2;
          const f32x4v lo = *(const f32x4v*)(smem + ABYTES + row * 256 + ((c2 ^ (row & 15)) << 4));
          const f32x4v hi = *(const f32x4v*)(smem + ABYTES + row * 256 + (((c2 + 1) ^ (row & 15)) << 4));
          b[ni] = cvt8(lo, hi);
        } else {
          b[ni] = *(const bf16x8v*)(smem + ABYTES + row * 128 + (((fch + kk * 4) ^ (row & 7)) << 4));
        }
      }
      #pragma unroll
      for (int mi = 0; mi < 4; ++mi)
        #pragma unroll
        for (int ni = 0; ni < 4; ++ni)
          acc[mi][ni] = __builtin_amdgcn_mfma_f32_16x16x32_bf16(a[mi], b[ni], acc[mi][ni], 0, 0, 0);
    }
    __syncthreads();
  }

  // Epilogue. C/D 16x16 mapping: col = lane&15, row = (lane>>4)*4 + reg.
  const long long coff = (long long)i0*p.sC0 + (long long)i1*p.sC1 +
                         (long long)i2*p.sC2 + (long long)i3*p.sC3 +
                         (long long)blockIdx.z*p.zC;
  const int col0 = bn + wc * 64 + (lane & 15);
  const int row0 = bm + wr * 64 + ((lane >> 4) << 2);
  if (OUT_F32) {
    float* Cp = (float*)p.C + coff;
    #pragma unroll
    for (int mi = 0; mi < 4; ++mi)
      #pragma unroll
      for (int ni = 0; ni < 4; ++ni)
        #pragma unroll
        for (int j = 0; j < 4; ++j)
          Cp[(size_t)(row0 + mi*16 + j) * p.ldc + (col0 + ni*16)] = acc[mi][ni][j] * p.scale;
  } else {
    bf16* Cp = (bf16*)p.C + coff;
    #pragma unroll
    for (int mi = 0; mi < 4; ++mi)
      #pragma unroll
      for (int ni = 0; ni < 4; ++ni)
        #pragma unroll
        for (int j = 0; j < 4; ++j)
          Cp[(size_t)(row0 + mi*16 + j) * p.ldc + (col0 + ni*16)] =
              __float2bfloat16(acc[mi][ni][j] * p.scale);
  }
}

// ---------------------------------------------------------------------------
// weight conversions
// ---------------------------------------------------------------------------
__global__ void cvt3_f32_bf16(const float* __restrict__ a0, const float* __restrict__ a1,
                              const float* __restrict__ a2,
                              unsigned short* __restrict__ out, long long ostride, int n4) {
  const int i = blockIdx.x * 256 + threadIdx.x;
  if (i >= n4) return;
  const float* src = (blockIdx.y == 0) ? a0 : (blockIdx.y == 1) ? a1 : a2;
  const float4 v = ((const float4*)src)[i];
  ushort4 o;
  o.x = f2bu(v.x); o.y = f2bu(v.y); o.z = f2bu(v.z); o.w = f2bu(v.w);
  ((ushort4*)(out + (size_t)blockIdx.y * ostride))[i] = o;
}

// Wpre[w][o][h*256 + i] = W_w[o][i*4 + h]   (head-interleave -> head-blocked)
__global__ void wpre_kernel(const float* __restrict__ Wout, const float* __restrict__ Woutd,
                            bf16* __restrict__ Wpre) {
  const int w = blockIdx.y;
  const int flat = blockIdx.x * 256 + threadIdx.x;   // 0..1M-1
  const float* Wsrc = w ? Woutd : Wout;
  const int o  = flat >> 10;
  const int c2 = flat & 1023;
  const int h  = c2 >> 8;
  const int i  = c2 & 255;
  Wpre[(size_t)w * 1048576 + flat] = __float2bfloat16(Wsrc[o * 1024 + i * 4 + h]);
}

// ---------------------------------------------------------------------------
// InstanceNorm + softmax on TRANSPOSED score partials (4 split-K slices,
// summed on the fly). Grid 256: block = (matrix m = bx>>2, quarter q = bx&3).
// Each block redundantly reduces mean/var over its full matrix (L2-resident),
// then handles 64 columns; each thread owns a quarter-column (j-range), with
// an LDS combine for the softmax denominator. No max pass: post-norm values
// are ~N(0,1) (z-max ~5), far from fp32 exp overflow; softmax shift-invariant.
// ---------------------------------------------------------------------------
__global__ __launch_bounds__(256)
void inorm_softmax_t4(const float* __restrict__ sp, bf16* __restrict__ pr) {
  const int m = blockIdx.x >> 2, q = blockIdx.x & 3;
  const size_t PS = 4194304;           // split-K partial stride (elements)
  const float* s = sp + (size_t)m * 65536;
  const int tid = threadIdx.x, lane = tid & 63, w = tid >> 6;

  float sum = 0.f, sq = 0.f;
  for (int i = tid; i < 16384; i += 256) {
    const float4 a = ((const float4*)s)[i];
    const float4 b = ((const float4*)(s + PS))[i];
    const float4 c = ((const float4*)(s + 2 * PS))[i];
    const float4 d = ((const float4*)(s + 3 * PS))[i];
    const float x0 = (a.x + b.x) + (c.x + d.x);
    const float x1 = (a.y + b.y) + (c.y + d.y);
    const float x2 = (a.z + b.z) + (c.z + d.z);
    const float x3 = (a.w + b.w) + (c.w + d.w);
    sum += (x0 + x1) + (x2 + x3);
    sq  += (x0 * x0 + x1 * x1) + (x2 * x2 + x3 * x3);
  }
  #pragma unroll
  for (int o = 32; o; o >>= 1) { sum += __shfl_xor(sum, o); sq += __shfl_xor(sq, o); }
  __shared__ float red[8];
  __shared__ float seb[256];
  if (lane == 0) { red[w] = sum; red[4 + w] = sq; }
  __syncthreads();
  sum = red[0] + red[1] + red[2] + red[3];
  sq  = red[4] + red[5] + red[6] + red[7];
  const float mean = sum * (1.f / 65536.f);
  const float var  = sq * (1.f / 65536.f) - mean * mean;
  const float inv  = rsqrtf(var + 1e-5f);

  const int col = q * 64 + (tid & 63);
  const int j0  = (tid >> 6) * 64;
  const float* cb = s + col;
  float se = 0.f;
  for (int j = j0; j < j0 + 64; ++j) {
    const size_t o = (size_t)j * 256;
    const float v = (cb[o] + cb[PS + o]) + (cb[2 * PS + o] + cb[3 * PS + o]);
    se += __expf((v - mean) * inv);
  }
  seb[tid] = se;
  __syncthreads();
  const int c64 = tid & 63;
  const float rvs = 1.f / (((seb[c64] + seb[c64 + 64]) + (seb[c64 + 128] + seb[c64 + 192])));
  bf16* pc = pr + (size_t)m * 65536 + col;
  for (int j = j0; j < j0 + 64; ++j) {
    const size_t o = (size_t)j * 256;
    const float v = (cb[o] + cb[PS + o]) + (cb[2 * PS + o] + cb[3 * PS + o]);
    pc[o] = __float2bfloat16(__expf((v - mean) * inv) * rvs);
  }
}

// ---------------------------------------------------------------------------
// Host orchestration
// ---------------------------------------------------------------------------
extern "C" void kernel_launch(void* const* d_in, const int* in_sizes, int n_in,
                              void* d_out, int out_size, void* d_ws, size_t ws_size,
                              hipStream_t stream)
{
  const float* S     = (const float*)d_in[0];
  const float* SKV   = (const float*)d_in[1];
  const float* T     = (const float*)d_in[2];
  const float* TKV   = (const float*)d_in[3];
  const float* Wq    = (const float*)d_in[4];
  const float* Wk    = (const float*)d_in[5];
  const float* Wv    = (const float*)d_in[6];
  const float* Wout  = (const float*)d_in[7];
  const float* Woutd = (const float*)d_in[8];
  float* out = (float*)d_out;

  const int Hd = 4, Dd = 256;
  const long long NC  = 4096ll * 1024;   // 4,194,304
  const long long BNC = 4 * NC;          // 16,777,216
  const long long HDN = 1048576;         // D*N per-head stride in QT/KT

  char* ws = (char*)d_ws;
  size_t off = 0;
  auto alloc = [&](size_t bytes) -> void* {
    void* pp = ws + off; off += (bytes + 255) & ~(size_t)255; return pp;
  };
  bf16*  Wqb    = (bf16*)alloc((size_t)Hd * Dd * Dd * 2);
  bf16*  Wkb    = (bf16*)alloc((size_t)Hd * Dd * Dd * 2);
  bf16*  Wvb    = (bf16*)alloc((size_t)Hd * Dd * Dd * 2);
  bf16*  Wpre   = (bf16*)alloc(2ull * 1024 * 1024 * 2);
  bf16*  QT     = (bf16*)alloc(2 * BNC * 2);          // [qi][b][h][i][n]
  bf16*  KT     = (bf16*)alloc(2 * BNC * 2);          // [ki][b][h][j][n]
  bf16*  Vc     = (bf16*)alloc(2 * BNC * 2);          // [vi][b][n][h*256+j]
  float* sparts = (float*)alloc(4ull * 4194304 * 4);  // 4 split-K partials of scT
  bf16*  probsT = (bf16*)alloc(64ull * 65536 * 2);    // [pp][b][h][j][i]
  bf16*  Weff   = QT;  // reuse: QT dead after scores GEMM
  if (ws_size < off) return;

  // 1) weight conversions (inputs are consumed fp32 directly by the GEMMs)
  {
    const int w4 = (Hd * Dd * Dd) / 4;
    cvt3_f32_bf16<<<dim3((w4 + 255) / 256, 3), dim3(256), 0, stream>>>(
        Wq, Wk, Wv, (unsigned short*)Wqb, (long long)Hd * Dd * Dd, w4);
    wpre_kernel<<<dim3(4096, 2), dim3(256), 0, stream>>>(Wout, Woutd, Wpre);
  }

  GemmP g{};

  // 2) Q projection: QT[qi][b][h][i][n] = sum_d Wq[h][i][d] * Xqi[b][n][h*256+d]
  //    A = Wq bf16, B = S/T fp32 (B2 select on qi).
  g.A = Wqb; g.B = S; g.A2 = nullptr; g.B2 = T; g.C = QT;
  g.K = 256; g.lda = 256; g.ldb = 1024; g.ldc = 4096; g.tilesN = 32; g.swz = 0;
  g.d0 = 4; g.d1 = 4; g.d2 = 2;                       // (h, b, qi)
  g.sA0 = 65536; g.sA1 = 0;  g.sA2 = 0;   g.sA3 = 0;
  g.sB0 = 256;   g.sB1 = NC; g.sB2 = 0;   g.sB3 = 0;
  g.sC0 = HDN;   g.sC1 = NC; g.sC2 = BNC; g.sC3 = 0;
  g.zA = 0; g.zB = 0; g.zC = 0;
  g.scale = 1.f;
  gemm_bt<0, 0, 1><<<dim3(2 * 32, 32), dim3(256), 0, stream>>>(g);

  // 3) K projection: same shape, B = SKV/TKV.
  g.A = Wkb; g.B = SKV; g.B2 = TKV; g.C = KT;
  gemm_bt<0, 0, 1><<<dim3(2 * 32, 32), dim3(256), 0, stream>>>(g);

  // 4) V projection: Vc[vi][b][n][h*256+j] = sum_d Xvi[b][n][h*256+d] * Wv[h][j][d]
  //    A = SKV/TKV fp32 (A2 select), B = Wv bf16.
  g.A = SKV; g.A2 = TKV; g.B = Wvb; g.B2 = nullptr; g.C = Vc;
  g.K = 256; g.lda = 1024; g.ldb = 256; g.ldc = 1024; g.tilesN = 2; g.swz = 0;
  g.sA0 = 256;   g.sA1 = NC; g.sA2 = 0; g.sA3 = 0;
  g.sB0 = 65536; g.sB1 = 0;  g.sB2 = 0; g.sB3 = 0;
  g.sC0 = 256;   g.sC1 = NC; g.sC2 = BNC; g.sC3 = 0;
  gemm_bt<0, 1, 0><<<dim3(32 * 2, 32), dim3(256), 0, stream>>>(g);

  // 5) scores split-K=4: scT_part[z][pp][b][h][j][i] = (1/32) sum_{n in slice z}
  //    KT[ki][j,n] * QT[qi][i,n]; pp = 2*qi+ki.
  g.A = KT; g.B = QT; g.A2 = nullptr; g.B2 = nullptr; g.C = sparts;
  g.K = 1024; g.lda = 4096; g.ldb = 4096; g.ldc = 256; g.tilesN = 2; g.swz = 0;
  g.d0 = 4; g.d1 = 4; g.d2 = 2;                       // (h, b, ki, qi)
  g.sA0 = HDN;   g.sA1 = NC;     g.sA2 = BNC;     g.sA3 = 0;
  g.sB0 = HDN;   g.sB1 = NC;     g.sB2 = 0;       g.sB3 = BNC;
  g.sC0 = 65536; g.sC1 = 262144; g.sC2 = 1048576; g.sC3 = 2097152;
  g.zA = 1024; g.zB = 1024; g.zC = 4194304;
  g.scale = 0.03125f;  // 1/sqrt(1024)
  gemm_bt<1, 0, 0><<<dim3(2 * 2, 64, 4), dim3(256), 0, stream>>>(g);

  // 6) fused partial-sum + InstanceNorm + softmax -> probsT [pp][b][h][j][i]
  inorm_softmax_t4<<<dim3(256), dim3(256), 0, stream>>>(sparts, probsT);

  // 7) Weff[2qi+ki][b][o][h*256+j] = sum_i Wpre[qi][o][h*256+i] * probsT[pp][b][h][j][i]
  g.A = Wpre; g.B = probsT; g.C = Weff;
  g.K = 256; g.lda = 1024; g.ldb = 256; g.ldc = 1024; g.tilesN = 2; g.swz = 0;
  g.d0 = 4; g.d1 = 4; g.d2 = 2;                       // (h, b, ki, qi)
  g.sA0 = 256;   g.sA1 = 0;       g.sA2 = 0;       g.sA3 = 1048576;
  g.sB0 = 65536; g.sB1 = 262144;  g.sB2 = 1048576; g.sB3 = 2097152;
  g.sC0 = 256;   g.sC1 = 1048576; g.sC2 = 4194304; g.sC3 = 8388608;
  g.zA = 0; g.zB = 0; g.zC = 0;
  g.scale = 1.f;
  gemm_bt<0, 0, 0><<<dim3(8 * 2, 64), dim3(256), 0, stream>>>(g);

  // 8) out[slot][b][n][o] = sum_{h,j} Vc[ki][b][n][h*256+j] * Weff[2qi+ki][b][o][h*256+j]
  //    slot = qi + 2*ki
  g.A = Vc; g.B = Weff; g.C = out;
  g.K = 1024; g.lda = 1024; g.ldb = 1024; g.ldc = 1024; g.tilesN = 8; g.swz = 1;
  g.d0 = 4; g.d1 = 2; g.d2 = 2;                       // (b, ki, qi)
  g.sA0 = NC;      g.sA1 = BNC;     g.sA2 = 0;       g.sA3 = 0;
  g.sB0 = 1048576; g.sB1 = 4194304; g.sB2 = 8388608; g.sB3 = 0;
  g.sC0 = NC;      g.sC1 = 2 * BNC; g.sC2 = BNC;     g.sC3 = 0;
  g.scale = 1.f;
  gemm_bt<1, 0, 0><<<dim3(32 * 8, 16), dim3(256), 0, stream>>>(g);

  (void)in_sizes; (void)n_in; (void)out_size;
}

// Round 4
// 445.315 us; speedup vs baseline: 1.4471x; 1.0623x over previous
//
#include <hip/hip_runtime.h>
#include <hip/hip_bf16.h>
#include <cstdint>

using bf16 = __hip_bfloat16;
typedef __attribute__((ext_vector_type(8))) short bf16x8v;
typedef __attribute__((ext_vector_type(4))) float f32x4v;

__device__ __forceinline__ void gload_lds16(const void* g, void* l) {
  __builtin_amdgcn_global_load_lds(
      (const __attribute__((address_space(1))) void*)g,
      (__attribute__((address_space(3))) void*)l, 16, 0, 0);
}

__device__ __forceinline__ unsigned short f2bu(float x) {
  union { __hip_bfloat16 h; unsigned short u; } cv;
  cv.h = __float2bfloat16(x);
  return cv.u;
}

__device__ __forceinline__ bf16x8v cvt8(const f32x4v lo, const f32x4v hi) {
  bf16x8v t;
  t[0] = (short)f2bu(lo[0]); t[1] = (short)f2bu(lo[1]);
  t[2] = (short)f2bu(lo[2]); t[3] = (short)f2bu(lo[3]);
  t[4] = (short)f2bu(hi[0]); t[5] = (short)f2bu(hi[1]);
  t[6] = (short)f2bu(hi[2]); t[7] = (short)f2bu(hi[3]);
  return t;
}

// ---------------------------------------------------------------------------
// Generic batched "bt" GEMM: C[m,n] = scale * sum_k A[m,k]*B[n,k]
// ---------------------------------------------------------------------------
struct GemmP {
  const void* A; const void* B; const void* A2; const void* B2; void* C;
  int K, lda, ldb, ldc, tilesN, swz;
  int d0, d1, d2;
  long long sA0, sA1, sA2, sA3;
  long long sB0, sB1, sB2, sB3;
  long long sC0, sC1, sC2, sC3;
  long long zA, zB, zC;
  float scale;
};

template<int OUT_F32, int AF32, int BF32>
__global__ __launch_bounds__(256, 4)
void gemm_bt(GemmP p)
{
  constexpr int EA = AF32 ? 4 : 2;
  constexpr int EB = BF32 ? 4 : 2;
  constexpr int ABYTES = 128 * 64 * EA;
  constexpr int BBYTES = 128 * 64 * EB;
  constexpr int SEGA = ABYTES / 4096;
  constexpr int SEGB = BBYTES / 4096;
  __shared__ __attribute__((aligned(1024))) char smem[ABYTES + BBYTES];
  const int tid  = threadIdx.x;
  const int lane = tid & 63;
  const int wid  = tid >> 6;

  int bx = blockIdx.x;
  if (p.swz) {
    const int nx = gridDim.x;
    const int q = nx >> 3, r = nx & 7;
    const int xcd = bx & 7, loc = bx >> 3;
    bx = (xcd < r ? xcd * (q + 1) : r * (q + 1) + (xcd - r) * q) + loc;
  }
  const int tn = bx % p.tilesN;
  const int tm = bx / p.tilesN;
  int idx = blockIdx.y;
  const int i0 = idx % p.d0; idx /= p.d0;
  const int i1 = idx % p.d1; idx /= p.d1;
  const int i2 = idx % p.d2;
  const int i3 = idx / p.d2;

  const char* Abase = (const char*)((p.A2 && i2) ? p.A2 : p.A);
  const char* Bbase = (const char*)((p.B2 && i2) ? p.B2 : p.B);
  const long long offA = (long long)i0*p.sA0 + (long long)i1*p.sA1 +
                         (long long)i2*p.sA2 + (long long)i3*p.sA3 +
                         (long long)blockIdx.z*p.zA;
  const long long offB = (long long)i0*p.sB0 + (long long)i1*p.sB1 +
                         (long long)i2*p.sB2 + (long long)i3*p.sB3 +
                         (long long)blockIdx.z*p.zB;
  const char* Am = Abase + offA * EA;
  const char* Bm = Bbase + offB * EB;
  const int bm = tm * 128, bn = tn * 128;

  const char* asrc[SEGA]; int aseg[SEGA];
  #pragma unroll
  for (int r = 0; r < SEGA; ++r) {
    const int oseg = (wid * SEGA + r) * 1024;
    const int o = oseg + lane * 16;
    int row, srcoff;
    if constexpr (AF32) { row = o >> 8; const int s = (o >> 4) & 15; srcoff = (s ^ (row & 15)) * 4; }
    else               { row = o >> 7; const int s = (o >> 4) & 7;  srcoff = (s ^ (row & 7)) * 8;  }
    aseg[r] = oseg;
    asrc[r] = Am + ((long long)(bm + row) * p.lda + srcoff) * EA;
  }
  const char* bsrc[SEGB]; int bseg[SEGB];
  #pragma unroll
  for (int r = 0; r < SEGB; ++r) {
    const int oseg = (wid * SEGB + r) * 1024;
    const int o = oseg + lane * 16;
    int row, srcoff;
    if constexpr (BF32) { row = o >> 8; const int s = (o >> 4) & 15; srcoff = (s ^ (row & 15)) * 4; }
    else               { row = o >> 7; const int s = (o >> 4) & 7;  srcoff = (s ^ (row & 7)) * 8;  }
    bseg[r] = oseg;
    bsrc[r] = Bm + ((long long)(bn + row) * p.ldb + srcoff) * EB;
  }

  f32x4v acc[4][4];
  #pragma unroll
  for (int i = 0; i < 4; ++i)
    #pragma unroll
    for (int j = 0; j < 4; ++j) acc[i][j] = (f32x4v){0.f, 0.f, 0.f, 0.f};

  const int wr = wid >> 1, wc = wid & 1;
  const int fr_a = wr * 64 + (lane & 15);
  const int fr_b = wc * 64 + (lane & 15);
  const int fch  = lane >> 4;

  const int nK = p.K / 64;
  for (int kt = 0; kt < nK; ++kt) {
    #pragma unroll
    for (int r = 0; r < SEGA; ++r) { gload_lds16(asrc[r], smem + aseg[r]); asrc[r] += 64 * EA; }
    #pragma unroll
    for (int r = 0; r < SEGB; ++r) { gload_lds16(bsrc[r], smem + ABYTES + bseg[r]); bsrc[r] += 64 * EB; }
    __syncthreads();
    #pragma unroll
    for (int kk = 0; kk < 2; ++kk) {
      bf16x8v a[4], b[4];
      #pragma unroll
      for (int mi = 0; mi < 4; ++mi) {
        const int row = fr_a + mi * 16;
        if constexpr (AF32) {
          const int c2 = (fch + kk * 4) * 2;
          const f32x4v lo = *(const f32x4v*)(smem + row * 256 + ((c2 ^ (row & 15)) << 4));
          const f32x4v hi = *(const f32x4v*)(smem + row * 256 + (((c2 + 1) ^ (row & 15)) << 4));
          a[mi] = cvt8(lo, hi);
        } else {
          a[mi] = *(const bf16x8v*)(smem + row * 128 + (((fch + kk * 4) ^ (row & 7)) << 4));
        }
      }
      #pragma unroll
      for (int ni = 0; ni < 4; ++ni) {
        const int row = fr_b + ni * 16;
        if constexpr (BF32) {
          const int c2 = (fch + kk * 4) * 2;
          const f32x4v lo = *(const f32x4v*)(smem + ABYTES + row * 256 + ((c2 ^ (row & 15)) << 4));
          const f32x4v hi = *(const f32x4v*)(smem + ABYTES + row * 256 + (((c2 + 1) ^ (row & 15)) << 4));
          b[ni] = cvt8(lo, hi);
        } else {
          b[ni] = *(const bf16x8v*)(smem + ABYTES + row * 128 + (((fch + kk * 4) ^ (row & 7)) << 4));
        }
      }
      #pragma unroll
      for (int mi = 0; mi < 4; ++mi)
        #pragma unroll
        for (int ni = 0; ni < 4; ++ni)
          acc[mi][ni] = __builtin_amdgcn_mfma_f32_16x16x32_bf16(a[mi], b[ni], acc[mi][ni], 0, 0, 0);
    }
    __syncthreads();
  }

  const long long coff = (long long)i0*p.sC0 + (long long)i1*p.sC1 +
                         (long long)i2*p.sC2 + (long long)i3*p.sC3 +
                         (long long)blockIdx.z*p.zC;
  const int col0 = bn + wc * 64 + (lane & 15);
  const int row0 = bm + wr * 64 + ((lane >> 4) << 2);
  if (OUT_F32) {
    float* Cp = (float*)p.C + coff;
    #pragma unroll
    for (int mi = 0; mi < 4; ++mi)
      #pragma unroll
      for (int ni = 0; ni < 4; ++ni)
        #pragma unroll
        for (int j = 0; j < 4; ++j)
          Cp[(size_t)(row0 + mi*16 + j) * p.ldc + (col0 + ni*16)] = acc[mi][ni][j] * p.scale;
  } else {
    bf16* Cp = (bf16*)p.C + coff;
    #pragma unroll
    for (int mi = 0; mi < 4; ++mi)
      #pragma unroll
      for (int ni = 0; ni < 4; ++ni)
        #pragma unroll
        for (int j = 0; j < 4; ++j)
          Cp[(size_t)(row0 + mi*16 + j) * p.ldc + (col0 + ni*16)] =
              __float2bfloat16(acc[mi][ni][j] * p.scale);
  }
}

// ---------------------------------------------------------------------------
// Fused K+V projection. Per block: one X fp32 tile [128 n][256 d] (staged in
// 64-step K-chunks) shared by both GEMMs:
//   K-tile[j,n] = sum_d Wk[j,d] * X[n,d]   (b_K frags == a_V frags == x)
//   V-tile[n,j] = sum_d X[n,d] * Wv[j,d]
// ---------------------------------------------------------------------------
struct KVP {
  const float* X0; const float* X1;   // SKV, TKV
  const bf16* Wk; const bf16* Wv;
  bf16* KT; bf16* Vc;
};

__global__ __launch_bounds__(256, 2)
void kv_fused(KVP p)
{
  __shared__ __attribute__((aligned(1024))) char smem[65536];  // X 32K | Wk 16K | Wv 16K
  const int tid = threadIdx.x, lane = tid & 63, wid = tid >> 6;
  const int jt = blockIdx.x & 1, nt = blockIdx.x >> 1;
  int idx = blockIdx.y;
  const int h = idx & 3; idx >>= 2;
  const int b = idx & 3; idx >>= 2;
  const int vi = idx;
  const float* X = (vi ? p.X1 : p.X0) + (size_t)b * 4194304 + (size_t)h * 256;
  const bf16* Wk = p.Wk + (size_t)h * 65536;
  const bf16* Wv = p.Wv + (size_t)h * 65536;
  const int n0 = nt * 128, j0 = jt * 128;

  const float* xsrc[8];
  #pragma unroll
  for (int r = 0; r < 8; ++r) {
    const int o = (wid * 8 + r) * 1024 + lane * 16;
    const int row = o >> 8, s = (o >> 4) & 15;
    xsrc[r] = X + (size_t)(n0 + row) * 1024 + (s ^ (row & 15)) * 4;
  }
  const bf16 *wksrc[4], *wvsrc[4];
  #pragma unroll
  for (int r = 0; r < 4; ++r) {
    const int o = (wid * 4 + r) * 1024 + lane * 16;
    const int row = o >> 7, s = (o >> 4) & 7;
    wksrc[r] = Wk + (size_t)(j0 + row) * 256 + (s ^ (row & 7)) * 8;
    wvsrc[r] = Wv + (size_t)(j0 + row) * 256 + (s ^ (row & 7)) * 8;
  }

  f32x4v accK[4][4], accV[4][4];
  #pragma unroll
  for (int i = 0; i < 4; ++i)
    #pragma unroll
    for (int j = 0; j < 4; ++j) {
      accK[i][j] = (f32x4v){0.f, 0.f, 0.f, 0.f};
      accV[i][j] = (f32x4v){0.f, 0.f, 0.f, 0.f};
    }

  const int wr = wid >> 1, wc = wid & 1;
  const int frW = wr * 64 + (lane & 15);   // Wk/Wv LDS rows (j)
  const int frX = wc * 64 + (lane & 15);   // X LDS rows (n)
  const int fch = lane >> 4;

  for (int kt = 0; kt < 4; ++kt) {
    #pragma unroll
    for (int r = 0; r < 8; ++r) { gload_lds16(xsrc[r], smem + (wid * 8 + r) * 1024); xsrc[r] += 64; }
    #pragma unroll
    for (int r = 0; r < 4; ++r) {
      gload_lds16(wksrc[r], smem + 32768 + (wid * 4 + r) * 1024); wksrc[r] += 64;
      gload_lds16(wvsrc[r], smem + 49152 + (wid * 4 + r) * 1024); wvsrc[r] += 64;
    }
    __syncthreads();
    #pragma unroll
    for (int kk = 0; kk < 2; ++kk) {
      bf16x8v wk[4], wv[4], x[4];
      #pragma unroll
      for (int mi = 0; mi < 4; ++mi) {
        const int row = frW + mi * 16;
        const int byo = row * 128 + (((fch + kk * 4) ^ (row & 7)) << 4);
        wk[mi] = *(const bf16x8v*)(smem + 32768 + byo);
        wv[mi] = *(const bf16x8v*)(smem + 49152 + byo);
      }
      #pragma unroll
      for (int ni = 0; ni < 4; ++ni) {
        const int row = frX + ni * 16;
        const int c2 = (fch + kk * 4) * 2;
        const f32x4v lo = *(const f32x4v*)(smem + row * 256 + ((c2 ^ (row & 15)) << 4));
        const f32x4v hi = *(const f32x4v*)(smem + row * 256 + (((c2 + 1) ^ (row & 15)) << 4));
        x[ni] = cvt8(lo, hi);
      }
      #pragma unroll
      for (int mi = 0; mi < 4; ++mi)
        #pragma unroll
        for (int ni = 0; ni < 4; ++ni) {
          accK[mi][ni] = __builtin_amdgcn_mfma_f32_16x16x32_bf16(wk[mi], x[ni], accK[mi][ni], 0, 0, 0);
          accV[ni][mi] = __builtin_amdgcn_mfma_f32_16x16x32_bf16(x[ni], wv[mi], accV[ni][mi], 0, 0, 0);
        }
    }
    __syncthreads();
  }

  // Epilogues. C/D map: col = lane&15 (B-frag), row = (lane>>4)*4 + reg (A-frag).
  const size_t kbase = (size_t)vi * 16777216 + (size_t)b * 4194304 + (size_t)h * 1048576;
  const size_t vbase = (size_t)vi * 16777216 + (size_t)b * 4194304;
  bf16* Kp = p.KT + kbase;
  bf16* Vp = p.Vc + vbase;
  const int rW = ((lane >> 4) << 2);
  #pragma unroll
  for (int mi = 0; mi < 4; ++mi)
    #pragma unroll
    for (int ni = 0; ni < 4; ++ni)
      #pragma unroll
      for (int j = 0; j < 4; ++j) {
        // K: row j-dim, col n-dim
        const int jrow = j0 + wr * 64 + mi * 16 + rW + j;
        const int ncol = n0 + wc * 64 + ni * 16 + (lane & 15);
        Kp[(size_t)jrow * 4096 + ncol] = __float2bfloat16(accK[mi][ni][j]);
        // V: row n-dim, col j-dim (accV[ni][mi])
        const int nrow = n0 + wc * 64 + ni * 16 + rW + j;
        const int jcol = j0 + wr * 64 + mi * 16 + (lane & 15);
        Vp[(size_t)nrow * 1024 + h * 256 + jcol] = __float2bfloat16(accV[ni][mi][j]);
      }
}

// ---------------------------------------------------------------------------
// weight conversions
// ---------------------------------------------------------------------------
__global__ void cvt3_f32_bf16(const float* __restrict__ a0, const float* __restrict__ a1,
                              const float* __restrict__ a2,
                              unsigned short* __restrict__ out, long long ostride, int n4) {
  const int i = blockIdx.x * 256 + threadIdx.x;
  if (i >= n4) return;
  const float* src = (blockIdx.y == 0) ? a0 : (blockIdx.y == 1) ? a1 : a2;
  const float4 v = ((const float4*)src)[i];
  ushort4 o;
  o.x = f2bu(v.x); o.y = f2bu(v.y); o.z = f2bu(v.z); o.w = f2bu(v.w);
  ((ushort4*)(out + (size_t)blockIdx.y * ostride))[i] = o;
}

__global__ void wpre_kernel(const float* __restrict__ Wout, const float* __restrict__ Woutd,
                            bf16* __restrict__ Wpre) {
  const int w = blockIdx.y;
  const int flat = blockIdx.x * 256 + threadIdx.x;
  const float* Wsrc = w ? Woutd : Wout;
  const int o  = flat >> 10;
  const int c2 = flat & 1023;
  const int h  = c2 >> 8;
  const int i  = c2 & 255;
  Wpre[(size_t)w * 1048576 + flat] = __float2bfloat16(Wsrc[o * 1024 + i * 4 + h]);
}

// ---------------------------------------------------------------------------
// Stage 1: per quarter-matrix sum/sumsq of z-summed scores (deterministic).
// Block bx: matrix m = bx>>2, j-quarter q = bx&3 (16384 contiguous elements).
// ---------------------------------------------------------------------------
__global__ __launch_bounds__(256)
void stats_quarter(const float* __restrict__ sp, float* __restrict__ st) {
  const int m = blockIdx.x >> 2, q = blockIdx.x & 3;
  const size_t PS = 4194304;
  const float* s = sp + (size_t)m * 65536 + (size_t)q * 16384;
  const int tid = threadIdx.x, lane = tid & 63, w = tid >> 6;

  float sum = 0.f, sq = 0.f;
  for (int i = tid; i < 4096; i += 256) {
    const float4 a = ((const float4*)s)[i];
    const float4 b = ((const float4*)(s + PS))[i];
    const float4 c = ((const float4*)(s + 2 * PS))[i];
    const float4 d = ((const float4*)(s + 3 * PS))[i];
    const float x0 = (a.x + b.x) + (c.x + d.x);
    const float x1 = (a.y + b.y) + (c.y + d.y);
    const float x2 = (a.z + b.z) + (c.z + d.z);
    const float x3 = (a.w + b.w) + (c.w + d.w);
    sum += (x0 + x1) + (x2 + x3);
    sq  += (x0 * x0 + x1 * x1) + (x2 * x2 + x3 * x3);
  }
  #pragma unroll
  for (int o = 32; o; o >>= 1) { sum += __shfl_xor(sum, o); sq += __shfl_xor(sq, o); }
  __shared__ float red[8];
  if (lane == 0) { red[w] = sum; red[4 + w] = sq; }
  __syncthreads();
  if (tid == 0) {
    st[blockIdx.x * 2]     = (red[0] + red[1]) + (red[2] + red[3]);
    st[blockIdx.x * 2 + 1] = (red[4] + red[5]) + (red[6] + red[7]);
  }
}

// ---------------------------------------------------------------------------
// Stage 2: combine quarter-stats -> mean/inv; softmax over j per column i.
// Block bx: matrix m = bx>>2, i-quarter iq = bx&3. Thread: column i (tid&63
// within quarter), j-sub-range jq = tid>>6 (64 rows), e[] kept in registers.
// ---------------------------------------------------------------------------
__global__ __launch_bounds__(256)
void softmax_t(const float* __restrict__ sp, const float* __restrict__ st,
               bf16* __restrict__ pr) {
  const int m = blockIdx.x >> 2, iq = blockIdx.x & 3;
  const size_t PS = 4194304;
  const float sum = (st[m*8+0] + st[m*8+2]) + (st[m*8+4] + st[m*8+6]);
  const float sq  = (st[m*8+1] + st[m*8+3]) + (st[m*8+5] + st[m*8+7]);
  const float mean = sum * (1.f / 65536.f);
  const float var  = sq * (1.f / 65536.f) - mean * mean;
  const float inv  = rsqrtf(var + 1e-5f);

  const int tid = threadIdx.x;
  const int i  = iq * 64 + (tid & 63);
  const int jq = tid >> 6;
  const float* cb = sp + (size_t)m * 65536 + i;

  float e[64];
  float se = 0.f;
  #pragma unroll
  for (int jj = 0; jj < 64; ++jj) {
    const size_t o = (size_t)(jq * 64 + jj) * 256;
    const float v = (cb[o] + cb[PS + o]) + (cb[2 * PS + o] + cb[3 * PS + o]);
    e[jj] = __expf((v - mean) * inv);
    se += e[jj];
  }
  __shared__ float seb[256];
  seb[tid] = se;
  __syncthreads();
  const int c = tid & 63;
  const float rvs = 1.f / ((seb[c] + seb[c + 64]) + (seb[c + 128] + seb[c + 192]));
  bf16* pc = pr + (size_t)m * 65536 + i;
  #pragma unroll
  for (int jj = 0; jj < 64; ++jj)
    pc[(size_t)(jq * 64 + jj) * 256] = __float2bfloat16(e[jj] * rvs);
}

// ---------------------------------------------------------------------------
// Host orchestration
// ---------------------------------------------------------------------------
extern "C" void kernel_launch(void* const* d_in, const int* in_sizes, int n_in,
                              void* d_out, int out_size, void* d_ws, size_t ws_size,
                              hipStream_t stream)
{
  const float* S     = (const float*)d_in[0];
  const float* SKV   = (const float*)d_in[1];
  const float* T     = (const float*)d_in[2];
  const float* TKV   = (const float*)d_in[3];
  const float* Wq    = (const float*)d_in[4];
  const float* Wk    = (const float*)d_in[5];
  const float* Wv    = (const float*)d_in[6];
  const float* Wout  = (const float*)d_in[7];
  const float* Woutd = (const float*)d_in[8];
  float* out = (float*)d_out;

  const int Hd = 4, Dd = 256;
  const long long NC  = 4096ll * 1024;
  const long long BNC = 4 * NC;
  const long long HDN = 1048576;

  char* ws = (char*)d_ws;
  size_t off = 0;
  auto alloc = [&](size_t bytes) -> void* {
    void* pp = ws + off; off += (bytes + 255) & ~(size_t)255; return pp;
  };
  bf16*  Wqb    = (bf16*)alloc((size_t)Hd * Dd * Dd * 2);
  bf16*  Wkb    = (bf16*)alloc((size_t)Hd * Dd * Dd * 2);
  bf16*  Wvb    = (bf16*)alloc((size_t)Hd * Dd * Dd * 2);
  bf16*  Wpre   = (bf16*)alloc(2ull * 1024 * 1024 * 2);
  bf16*  QT     = (bf16*)alloc(2 * BNC * 2);          // [qi][b][h][i][n]
  bf16*  KT     = (bf16*)alloc(2 * BNC * 2);          // [ki][b][h][j][n]
  bf16*  Vc     = (bf16*)alloc(2 * BNC * 2);          // [vi][b][n][h*256+j]
  float* sparts = (float*)alloc(4ull * 4194304 * 4);  // 4 split-K partials of scT
  float* stats  = (float*)alloc(256ull * 2 * 4);      // per quarter sum/sumsq
  bf16*  probsT = (bf16*)alloc(64ull * 65536 * 2);    // [pp][b][h][j][i]
  bf16*  Weff   = QT;  // reuse: QT dead after scores GEMM
  if (ws_size < off) return;

  // 1) weight conversions
  {
    const int w4 = (Hd * Dd * Dd) / 4;
    cvt3_f32_bf16<<<dim3((w4 + 255) / 256, 3), dim3(256), 0, stream>>>(
        Wq, Wk, Wv, (unsigned short*)Wqb, (long long)Hd * Dd * Dd, w4);
    wpre_kernel<<<dim3(4096, 2), dim3(256), 0, stream>>>(Wout, Woutd, Wpre);
  }

  GemmP g{};

  // 2) Q projection: QT[qi][b][h][i][n] = sum_d Wq[h][i][d] * Xqi[b][n][h*256+d]
  g.A = Wqb; g.B = S; g.A2 = nullptr; g.B2 = T; g.C = QT;
  g.K = 256; g.lda = 256; g.ldb = 1024; g.ldc = 4096; g.tilesN = 32; g.swz = 0;
  g.d0 = 4; g.d1 = 4; g.d2 = 2;                       // (h, b, qi)
  g.sA0 = 65536; g.sA1 = 0;  g.sA2 = 0;   g.sA3 = 0;
  g.sB0 = 256;   g.sB1 = NC; g.sB2 = 0;   g.sB3 = 0;
  g.sC0 = HDN;   g.sC1 = NC; g.sC2 = BNC; g.sC3 = 0;
  g.zA = 0; g.zB = 0; g.zC = 0;
  g.scale = 1.f;
  gemm_bt<0, 0, 1><<<dim3(2 * 32, 32), dim3(256), 0, stream>>>(g);

  // 3) fused K+V projection
  {
    KVP kv{SKV, TKV, Wkb, Wvb, KT, Vc};
    kv_fused<<<dim3(64, 32), dim3(256), 0, stream>>>(kv);
  }

  // 4) scores split-K=4: sparts[z][pp][b][h][j][i] = (1/32) sum_{n slice z}
  //    KT[ki][j,n] * QT[qi][i,n]; pp = 2*qi+ki.
  g.A = KT; g.B = QT; g.A2 = nullptr; g.B2 = nullptr; g.C = sparts;
  g.K = 1024; g.lda = 4096; g.ldb = 4096; g.ldc = 256; g.tilesN = 2; g.swz = 0;
  g.d0 = 4; g.d1 = 4; g.d2 = 2;                       // (h, b, ki, qi)
  g.sA0 = HDN;   g.sA1 = NC;     g.sA2 = BNC;     g.sA3 = 0;
  g.sB0 = HDN;   g.sB1 = NC;     g.sB2 = 0;       g.sB3 = BNC;
  g.sC0 = 65536; g.sC1 = 262144; g.sC2 = 1048576; g.sC3 = 2097152;
  g.zA = 1024; g.zB = 1024; g.zC = 4194304;
  g.scale = 0.03125f;
  gemm_bt<1, 0, 0><<<dim3(2 * 2, 64, 4), dim3(256), 0, stream>>>(g);

  // 5) stats + softmax (InstanceNorm over matrix, softmax over j per col i)
  stats_quarter<<<dim3(256), dim3(256), 0, stream>>>(sparts, stats);
  softmax_t<<<dim3(256), dim3(256), 0, stream>>>(sparts, stats, probsT);

  // 6) Weff[2qi+ki][b][o][h*256+j] = sum_i Wpre[qi][o][h*256+i] * probsT[pp][b][h][j][i]
  g.A = Wpre; g.B = probsT; g.C = Weff;
  g.K = 256; g.lda = 1024; g.ldb = 256; g.ldc = 1024; g.tilesN = 2; g.swz = 0;
  g.d0 = 4; g.d1 = 4; g.d2 = 2;                       // (h, b, ki, qi)
  g.sA0 = 256;   g.sA1 = 0;       g.sA2 = 0;       g.sA3 = 1048576;
  g.sB0 = 65536; g.sB1 = 262144;  g.sB2 = 1048576; g.sB3 = 2097152;
  g.sC0 = 256;   g.sC1 = 1048576; g.sC2 = 4194304; g.sC3 = 8388608;
  g.zA = 0; g.zB = 0; g.zC = 0;
  g.scale = 1.f;
  gemm_bt<0, 0, 0><<<dim3(8 * 2, 64), dim3(256), 0, stream>>>(g);

  // 7) out[slot][b][n][o] = sum_{h,j} Vc[ki][b][n][h*256+j] * Weff[2qi+ki][b][o][h*256+j]
  g.A = Vc; g.B = Weff; g.C = out;
  g.K = 1024; g.lda = 1024; g.ldb = 1024; g.ldc = 1024; g.tilesN = 8; g.swz = 1;
  g.d0 = 4; g.d1 = 2; g.d2 = 2;                       // (b, ki, qi)
  g.sA0 = NC;      g.sA1 = BNC;     g.sA2 = 0;       g.sA3 = 0;
  g.sB0 = 1048576; g.sB1 = 4194304; g.sB2 = 8388608; g.sB3 = 0;
  g.sC0 = NC;      g.sC1 = 2 * BNC; g.sC2 = BNC;     g.sC3 = 0;
  g.scale = 1.f;
  gemm_bt<1, 0, 0><<<dim3(32 * 8, 16), dim3(256), 0, stream>>>(g);

  (void)in_sizes; (void)n_in; (void)out_size;
}